// Round 5
// baseline (950.658 us; speedup 1.0000x reference)
//
#include <hip/hip_runtime.h>
#include <stdint.h>
#include <stddef.h>

typedef float f32x4 __attribute__((ext_vector_type(4)));
typedef int i32x8 __attribute__((ext_vector_type(8)));

union Frag32 { long l[4]; i32x8 v; };  // 32 bytes = one scaled-MFMA operand/lane

// ---------------------------------------------------------------------------
// Quantized operands live in an "LDS-image" layout: 8 KB slots; slot
// s = blk*(K/32) + ksl holds rows [blk*256..+256) x k-bytes [ksl*32..+32),
// logical L = row*32 + kkb stored at P = L ^ (((L>>7)&3)<<3).
// GEMM stages a slot with a LINEAR contiguous copy (global_load_lds x16);
// fragment ds_read_b64 at P = row*32 + ((j ^ ((row>>2)&3))*8) hits a
// bijective bank-pair pattern: zero conflicts (verified R3/R4: SQ_LDS_BANK_CONFLICT=0).
//
// GEMM inner op: mfma_scale_f32_16x16x128_f8f6f4 with unit E8M0 scales
// (0x7F per byte -> x1.0): bit-exact fp8 matmul at the 2x MX rate
// (verified R4: absmax 0.03 vs threshold, same as non-scaled).
//
// Workspace layout (bytes):
//   [0..7]    : two u32 atomic absmax slots (w_absmax_bits, x_absmax_bits)
//   [8..255]  : scales: idx2=1/w_scale, idx3=1/x_scale, idx4=w_scale*x_scale
//   [256 .. 256+M*K)            : x_q  LDS-image slots (32 MB)
//   [256+M*K .. 256+M*K+N*K)    : w_qT LDS-image slots (64 MB)
// ---------------------------------------------------------------------------

__global__ void absmax_kernel(const float4* __restrict__ x, size_t n4,
                              unsigned int* __restrict__ out) {
  size_t idx = (size_t)blockIdx.x * blockDim.x + threadIdx.x;
  size_t stride = (size_t)gridDim.x * blockDim.x;
  float m = 0.f;
  for (size_t i = idx; i < n4; i += stride) {
    float4 v = x[i];
    m = fmaxf(m, fmaxf(fmaxf(fabsf(v.x), fabsf(v.y)),
                       fmaxf(fabsf(v.z), fabsf(v.w))));
  }
#pragma unroll
  for (int off = 32; off > 0; off >>= 1)
    m = fmaxf(m, __shfl_xor(m, off));
  if ((threadIdx.x & 63) == 0)
    atomicMax(out, __float_as_uint(m));  // all values >= 0: uint order == float order
}

__global__ void scales_kernel(float* __restrict__ s) {
  const unsigned int* u = (const unsigned int*)s;
  float wmax = __uint_as_float(u[0]);
  float xmax = __uint_as_float(u[1]);
  float w_scale = wmax / 448.0f;
  float x_scale = xmax / 448.0f;
  s[2] = 1.0f / w_scale;
  s[3] = 1.0f / x_scale;
  s[4] = x_scale * w_scale;
}

// x [M][K] f32 -> LDS-image slots. One thread = one 16B logical chunk.
__global__ void quantize_x_kernel(const float4* __restrict__ x,
                                  uint8_t* __restrict__ xq,
                                  const float* __restrict__ scales,
                                  int K, int n_chunks) {
  const float inv = scales[3];
  const int kslots = K >> 5;
  int idx = blockIdx.x * blockDim.x + threadIdx.x;
  const int stride = gridDim.x * blockDim.x;
  for (; idx < n_chunks; idx += stride) {
    const int slot = idx >> 9;        // 512 chunks of 16B per 8KB slot
    const int p16 = idx & 511;
    const int row = p16 >> 1;
    const int kkb0 = (p16 & 1) << 4;
    const int mblk = slot / kslots;
    const int ksl = slot - mblk * kslots;
    const size_t f4 = ((size_t)(mblk * 256 + row) * K + ksl * 32 + kkb0) >> 2;
    const float4 v0 = x[f4 + 0], v1 = x[f4 + 1], v2 = x[f4 + 2], v3 = x[f4 + 3];
    uint32_t c0 = __builtin_amdgcn_cvt_pk_fp8_f32(v0.x * inv, v0.y * inv, 0, false);
    c0 = __builtin_amdgcn_cvt_pk_fp8_f32(v0.z * inv, v0.w * inv, c0, true);
    uint32_t c1 = __builtin_amdgcn_cvt_pk_fp8_f32(v1.x * inv, v1.y * inv, 0, false);
    c1 = __builtin_amdgcn_cvt_pk_fp8_f32(v1.z * inv, v1.w * inv, c1, true);
    uint32_t c2 = __builtin_amdgcn_cvt_pk_fp8_f32(v2.x * inv, v2.y * inv, 0, false);
    c2 = __builtin_amdgcn_cvt_pk_fp8_f32(v2.z * inv, v2.w * inv, c2, true);
    uint32_t c3 = __builtin_amdgcn_cvt_pk_fp8_f32(v3.x * inv, v3.y * inv, 0, false);
    c3 = __builtin_amdgcn_cvt_pk_fp8_f32(v3.z * inv, v3.w * inv, c3, true);
    const unsigned long long L0 = (unsigned long long)c0 | ((unsigned long long)c1 << 32);
    const unsigned long long L1 = (unsigned long long)c2 | ((unsigned long long)c3 << 32);
    const int Lc = row * 32 + kkb0;
    const int mask = ((row >> 2) & 3) << 3;
    const int addr0 = Lc ^ (mask & 16);
    uint8_t* p = xq + (size_t)slot * 8192;
    *(unsigned long long*)(p + addr0 + (mask & 8)) = L0;
    *(unsigned long long*)(p + addr0 + (8 ^ (mask & 8))) = L1;
  }
}

// w [K][N] f32 -> w^T LDS-image slots (row = n, 256-row blocks).
__global__ void quantize_wT_kernel(const float* __restrict__ w,
                                   uint8_t* __restrict__ wqt,
                                   const float* __restrict__ scales,
                                   int N, int K) {
  __shared__ uint8_t tile[64][68];  // [k][n], padded
  const float inv = scales[2];
  const int tn = blockIdx.x;
  const int tk = blockIdx.y;
  const int t = threadIdx.x;
  {
    const int rr = t >> 4;
    const int cc4 = t & 15;
#pragma unroll
    for (int i = 0; i < 4; ++i) {
      const int row = rr + i * 16;  // k within tile
      const float4 v = *(const float4*)&w[(size_t)(tk * 64 + row) * N + tn * 64 + cc4 * 4];
      uint32_t c = __builtin_amdgcn_cvt_pk_fp8_f32(v.x * inv, v.y * inv, 0, false);
      c = __builtin_amdgcn_cvt_pk_fp8_f32(v.z * inv, v.w * inv, c, true);
      *(uint32_t*)&tile[row][cc4 * 4] = c;
    }
  }
  __syncthreads();
  {
    const int nrow = t & 63;
    const int kc16 = t >> 6;
    unsigned long long L0 = 0, L1 = 0;
#pragma unroll
    for (int j = 0; j < 8; ++j)
      L0 |= (unsigned long long)tile[kc16 * 16 + j][nrow] << (8 * j);
#pragma unroll
    for (int j = 0; j < 8; ++j)
      L1 |= (unsigned long long)tile[kc16 * 16 + 8 + j][nrow] << (8 * j);
    const int n_g = tn * 64 + nrow;
    const int k0g = tk * 64 + kc16 * 16;
    const size_t slot = (size_t)(n_g >> 8) * (K >> 5) + (k0g >> 5);
    const int row = n_g & 255;
    const int kkb0 = k0g & 31;
    const int Lc = row * 32 + kkb0;
    const int mask = ((row >> 2) & 3) << 3;
    const int addr0 = Lc ^ (mask & 16);
    uint8_t* p = wqt + slot * 8192;
    *(unsigned long long*)(p + addr0 + (mask & 8)) = L0;
    *(unsigned long long*)(p + addr0 + (8 ^ (mask & 8))) = L1;
  }
}

// ---------------------------------------------------------------------------
// fp8 GEMM, 256x256 tile, MX-scaled 16x16x128 MFMA, fine-pipelined phases:
//   stage-first (full-phase flight) -> b-frags -> a-frags pipelined one
//   8-MFMA cluster ahead -> vmcnt(0)+barrier once per phase.
//   Compiler manages all lgkmcnt (counted, interleaved) — no manual drains.
// ---------------------------------------------------------------------------
#define T_BM 256
#define T_BN 256
#define T_BK 128
#define UNIT_SCALE 0x7F7F7F7F

__device__ __forceinline__ void gl_lds16(const uint8_t* g, uint8_t* lds) {
  __builtin_amdgcn_global_load_lds(
      (const __attribute__((address_space(1))) void*)g,
      (__attribute__((address_space(3))) void*)lds, 16, 0, 0);
}

__global__ __launch_bounds__(512, 2) void gemm_fp8_mx(
    const uint8_t* __restrict__ Aq, const uint8_t* __restrict__ BqT,
    const float* __restrict__ bias, const float* __restrict__ scales,
    float* __restrict__ C, int M, int N, int K) {
  extern __shared__ uint8_t smem[];
  uint8_t* const Ab = smem;            // 8 slots x 8192 = 64 KB
  uint8_t* const Bb = smem + 65536;    // 8 slots x 8192 = 64 KB

  const int ntn = N / T_BN;
  const int bid = blockIdx.x;
  const int m0 = (bid / ntn) * T_BM;
  const int n0 = (bid % ntn) * T_BN;

  const int tid = threadIdx.x;
  const int w = tid >> 6;      // wave 0..7
  const int l = tid & 63;
  const int wr = w >> 2;       // 0..1  (M half)
  const int wc = w & 3;        // 0..3  (N quarter)

  const int kslots = K >> 5;

  // staging: linear contiguous copy of one 8KB slot; wave w owns bytes
  // [w*1024, w*1024+1024), lane l the 16B at +l*16.
  const int soff = w * 1024 + l * 16;
  const uint8_t* a_src = Aq + (size_t)(m0 >> 8) * kslots * 8192 + soff;
  const uint8_t* b_src = BqT + (size_t)(n0 >> 8) * kslots * 8192 + soff;

  // fragment-read constants: lane's quarter kq reads slice/slot kq only.
  const int fro = l & 15;
  const int kq = l >> 4;
  const int fswz = ((fro >> 2) & 3) << 3;
  int aoff[4], boff[4];
#pragma unroll
  for (int j = 0; j < 4; ++j) {
    const int js = (j * 8) ^ fswz;
    aoff[j] = (wr * 128 + fro) * 32 + js;
    boff[j] = (wc * 64 + fro) * 32 + js;
  }

  f32x4 acc[8][4] = {};

  const int NT = K / T_BK;  // 32 K-tiles

#define LDA_(dst, mi)                                                   \
  do {                                                                  \
    _Pragma("unroll") for (int j = 0; j < 4; ++j)                       \
        dst.l[j] = *(const long*)(Aslot + aoff[j] + (mi)*512);          \
  } while (0)

#define CLUSTER_(mi, f0, f1)                                            \
  do {                                                                  \
    __builtin_amdgcn_s_setprio(1);                                      \
    _Pragma("unroll") for (int n = 0; n < 4; ++n)                       \
        acc[mi][n] = __builtin_amdgcn_mfma_scale_f32_16x16x128_f8f6f4(  \
            f0.v, b4[n].v, acc[mi][n], 0, 0, 0, UNIT_SCALE, 0,          \
            UNIT_SCALE);                                                \
    _Pragma("unroll") for (int n = 0; n < 4; ++n)                       \
        acc[(mi) + 1][n] =                                              \
            __builtin_amdgcn_mfma_scale_f32_16x16x128_f8f6f4(           \
                f1.v, b4[n].v, acc[(mi) + 1][n], 0, 0, 0, UNIT_SCALE,   \
                0, UNIT_SCALE);                                         \
    __builtin_amdgcn_s_setprio(0);                                      \
  } while (0)

  // prologue: stage K-tile 0 into slots 0..3
#pragma unroll
  for (int kk = 0; kk < 4; ++kk) {
    gl_lds16(a_src + (size_t)kk * 8192, Ab + kk * 8192 + soff);
    gl_lds16(b_src + (size_t)kk * 8192, Bb + kk * 8192 + soff);
  }
  asm volatile("s_waitcnt vmcnt(0)" ::: "memory");
  __builtin_amdgcn_s_barrier();

  const uint8_t* an = a_src + 4 * 8192;  // next K-tile staging src
  const uint8_t* bn = b_src + 4 * 8192;

  for (int kt = 0; kt < NT; ++kt) {
    const int sb = (kt & 1) * 4;   // this K-tile's slots
    const int sb2 = 4 - sb;        // next K-tile's slots
    const uint8_t* Aslot = Ab + (sb + kq) * 8192;
    const uint8_t* Bslot = Bb + (sb + kq) * 8192;

    // 1. stage K-tile kt+1 FIRST: flight = the whole phase
#pragma unroll
    for (int kk = 0; kk < 4; ++kk) {
      gl_lds16(an + (size_t)kk * 8192, Ab + (sb2 + kk) * 8192 + soff);
      gl_lds16(bn + (size_t)kk * 8192, Bb + (sb2 + kk) * 8192 + soff);
    }
    if (kt + 2 < NT) { an += 4 * 8192; bn += 4 * 8192; }  // clamp keeps tail uniform

    // 2. b-fragments (reused by all clusters)
    Frag32 b4[4];
#pragma unroll
    for (int n = 0; n < 4; ++n)
#pragma unroll
      for (int j = 0; j < 4; ++j)
        b4[n].l[j] = *(const long*)(Bslot + boff[j] + n * 512);

    // 3. a-fragments pipelined one 8-MFMA cluster ahead (static names)
    Frag32 p0, p1, q0, q1;
    LDA_(p0, 0); LDA_(p1, 1);
    LDA_(q0, 2); LDA_(q1, 3);
    CLUSTER_(0, p0, p1);
    LDA_(p0, 4); LDA_(p1, 5);
    CLUSTER_(2, q0, q1);
    LDA_(q0, 6); LDA_(q1, 7);
    CLUSTER_(4, p0, p1);
    CLUSTER_(6, q0, q1);

    // 4. kt+1's loads have had the whole phase to fly
    asm volatile("s_waitcnt vmcnt(0)" ::: "memory");
    __builtin_amdgcn_s_barrier();
  }

  // epilogue: C = acc * (x_scale*w_scale) + bias
  const float s = scales[4];
  const int crow = m0 + wr * 128 + (l >> 4) * 4;
  const int ccol = n0 + wc * 64 + (l & 15);
#pragma unroll
  for (int n = 0; n < 4; ++n) {
    const int col = ccol + n * 16;
    const float bv = bias[col];
#pragma unroll
    for (int m = 0; m < 8; ++m) {
      const int row = crow + m * 16;
#pragma unroll
      for (int r = 0; r < 4; ++r)
        C[(size_t)(row + r) * N + col] = acc[m][n][r] * s + bv;
    }
  }
}

extern "C" void kernel_launch(void* const* d_in, const int* in_sizes, int n_in,
                              void* d_out, int out_size, void* d_ws, size_t ws_size,
                              hipStream_t stream) {
  const float* inp = (const float*)d_in[0];
  const float* weight = (const float*)d_in[1];
  const float* bias = (const float*)d_in[2];
  float* out = (float*)d_out;

  const int N = in_sizes[2];                 // 16384
  const int K = in_sizes[1] / N;             // 4096
  const int M = in_sizes[0] / K;             // 8192

  uint8_t* ws = (uint8_t*)d_ws;
  float* scales = (float*)ws;
  uint8_t* xq = ws + 256;
  uint8_t* wqt = ws + 256 + (size_t)M * K;

  hipMemsetAsync(d_ws, 0, 256, stream);

  absmax_kernel<<<2048, 256, 0, stream>>>((const float4*)weight,
                                          (size_t)K * N / 4,
                                          (unsigned int*)ws + 0);
  absmax_kernel<<<2048, 256, 0, stream>>>((const float4*)inp,
                                          (size_t)M * K / 4,
                                          (unsigned int*)ws + 1);
  scales_kernel<<<1, 1, 0, stream>>>(scales);

  quantize_x_kernel<<<4096, 256, 0, stream>>>((const float4*)inp, xq, scales,
                                              K, M * K / 16);
  quantize_wT_kernel<<<dim3(N / 64, K / 64), 256, 0, stream>>>(weight, wqt,
                                                               scales, N, K);

  gemm_fp8_mx<<<(M / T_BM) * (N / T_BN), 512, 131072, stream>>>(
      xq, wqt, bias, scales, out, M, N, K);
}

// Round 6
// 886.819 us; speedup vs baseline: 1.0720x; 1.0720x over previous
//
#include <hip/hip_runtime.h>
#include <stdint.h>
#include <stddef.h>

typedef float f32x16 __attribute__((ext_vector_type(16)));
typedef int i32x8 __attribute__((ext_vector_type(8)));

union Frag32 { long l[4]; i32x8 v; };  // 32 bytes = one scaled-MFMA operand/lane

// ---------------------------------------------------------------------------
// Quantized operands live in an "LDS-image" layout: 8 KB slots; slot
// s = blk*(K/32) + ksl holds rows [blk*256..+256) x k-bytes [ksl*32..+32),
// logical L = row*32 + kkb stored at P = L ^ (((L>>7)&3)<<3).
// GEMM stages SLICES (2 consecutive slots = 64 k-bytes = 16 KB) with a
// LINEAR contiguous copy (global_load_lds x16); fragment ds_read_b64 at
// P = h*8192 + row*32 + ((j ^ ((row>>2)&3))*8) is bank-pair-bijective per
// half-wave: zero conflicts (R3/R4/R5 verified: SQ_LDS_BANK_CONFLICT=0).
//
// GEMM inner op: mfma_scale_f32_32x32x64_f8f6f4 with unit E8M0 scales
// (0x7F/byte -> x1.0): bit-exact fp8 matmul at the 2x MX rate.
// Lane operand mapping: row/col = l&31, k-half h = l>>5 (32 B = one slot row).
//
// Workspace layout (bytes):
//   [0..7]    : two u32 atomic absmax slots (w_absmax_bits, x_absmax_bits)
//   [8..255]  : scales: idx2=1/w_scale, idx3=1/x_scale, idx4=w_scale*x_scale
//   [256 .. 256+M*K)            : x_q  LDS-image slots (32 MB)
//   [256+M*K .. 256+M*K+N*K)    : w_qT LDS-image slots (64 MB)
// ---------------------------------------------------------------------------

__global__ void absmax_kernel(const float4* __restrict__ x, size_t n4,
                              unsigned int* __restrict__ out) {
  size_t idx = (size_t)blockIdx.x * blockDim.x + threadIdx.x;
  size_t stride = (size_t)gridDim.x * blockDim.x;
  float m = 0.f;
  for (size_t i = idx; i < n4; i += stride) {
    float4 v = x[i];
    m = fmaxf(m, fmaxf(fmaxf(fabsf(v.x), fabsf(v.y)),
                       fmaxf(fabsf(v.z), fabsf(v.w))));
  }
#pragma unroll
  for (int off = 32; off > 0; off >>= 1)
    m = fmaxf(m, __shfl_xor(m, off));
  if ((threadIdx.x & 63) == 0)
    atomicMax(out, __float_as_uint(m));  // all values >= 0: uint order == float order
}

__global__ void scales_kernel(float* __restrict__ s) {
  const unsigned int* u = (const unsigned int*)s;
  float wmax = __uint_as_float(u[0]);
  float xmax = __uint_as_float(u[1]);
  float w_scale = wmax / 448.0f;
  float x_scale = xmax / 448.0f;
  s[2] = 1.0f / w_scale;
  s[3] = 1.0f / x_scale;
  s[4] = x_scale * w_scale;
}

// x [M][K] f32 -> LDS-image slots. One thread = one 16B logical chunk.
__global__ void quantize_x_kernel(const float4* __restrict__ x,
                                  uint8_t* __restrict__ xq,
                                  const float* __restrict__ scales,
                                  int K, int n_chunks) {
  const float inv = scales[3];
  const int kslots = K >> 5;
  int idx = blockIdx.x * blockDim.x + threadIdx.x;
  const int stride = gridDim.x * blockDim.x;
  for (; idx < n_chunks; idx += stride) {
    const int slot = idx >> 9;        // 512 chunks of 16B per 8KB slot
    const int p16 = idx & 511;
    const int row = p16 >> 1;
    const int kkb0 = (p16 & 1) << 4;
    const int mblk = slot / kslots;
    const int ksl = slot - mblk * kslots;
    const size_t f4 = ((size_t)(mblk * 256 + row) * K + ksl * 32 + kkb0) >> 2;
    const float4 v0 = x[f4 + 0], v1 = x[f4 + 1], v2 = x[f4 + 2], v3 = x[f4 + 3];
    uint32_t c0 = __builtin_amdgcn_cvt_pk_fp8_f32(v0.x * inv, v0.y * inv, 0, false);
    c0 = __builtin_amdgcn_cvt_pk_fp8_f32(v0.z * inv, v0.w * inv, c0, true);
    uint32_t c1 = __builtin_amdgcn_cvt_pk_fp8_f32(v1.x * inv, v1.y * inv, 0, false);
    c1 = __builtin_amdgcn_cvt_pk_fp8_f32(v1.z * inv, v1.w * inv, c1, true);
    uint32_t c2 = __builtin_amdgcn_cvt_pk_fp8_f32(v2.x * inv, v2.y * inv, 0, false);
    c2 = __builtin_amdgcn_cvt_pk_fp8_f32(v2.z * inv, v2.w * inv, c2, true);
    uint32_t c3 = __builtin_amdgcn_cvt_pk_fp8_f32(v3.x * inv, v3.y * inv, 0, false);
    c3 = __builtin_amdgcn_cvt_pk_fp8_f32(v3.z * inv, v3.w * inv, c3, true);
    const unsigned long long L0 = (unsigned long long)c0 | ((unsigned long long)c1 << 32);
    const unsigned long long L1 = (unsigned long long)c2 | ((unsigned long long)c3 << 32);
    const int Lc = row * 32 + kkb0;
    const int mask = ((row >> 2) & 3) << 3;
    const int addr0 = Lc ^ (mask & 16);
    uint8_t* p = xq + (size_t)slot * 8192;
    *(unsigned long long*)(p + addr0 + (mask & 8)) = L0;
    *(unsigned long long*)(p + addr0 + (8 ^ (mask & 8))) = L1;
  }
}

// w [K][N] f32 -> w^T LDS-image slots (row = n, 256-row blocks).
__global__ void quantize_wT_kernel(const float* __restrict__ w,
                                   uint8_t* __restrict__ wqt,
                                   const float* __restrict__ scales,
                                   int N, int K) {
  __shared__ uint8_t tile[64][68];  // [k][n], padded
  const float inv = scales[2];
  const int tn = blockIdx.x;
  const int tk = blockIdx.y;
  const int t = threadIdx.x;
  {
    const int rr = t >> 4;
    const int cc4 = t & 15;
#pragma unroll
    for (int i = 0; i < 4; ++i) {
      const int row = rr + i * 16;  // k within tile
      const float4 v = *(const float4*)&w[(size_t)(tk * 64 + row) * N + tn * 64 + cc4 * 4];
      uint32_t c = __builtin_amdgcn_cvt_pk_fp8_f32(v.x * inv, v.y * inv, 0, false);
      c = __builtin_amdgcn_cvt_pk_fp8_f32(v.z * inv, v.w * inv, c, true);
      *(uint32_t*)&tile[row][cc4 * 4] = c;
    }
  }
  __syncthreads();
  {
    const int nrow = t & 63;
    const int kc16 = t >> 6;
    unsigned long long L0 = 0, L1 = 0;
#pragma unroll
    for (int j = 0; j < 8; ++j)
      L0 |= (unsigned long long)tile[kc16 * 16 + j][nrow] << (8 * j);
#pragma unroll
    for (int j = 0; j < 8; ++j)
      L1 |= (unsigned long long)tile[kc16 * 16 + 8 + j][nrow] << (8 * j);
    const int n_g = tn * 64 + nrow;
    const int k0g = tk * 64 + kc16 * 16;
    const size_t slot = (size_t)(n_g >> 8) * (K >> 5) + (k0g >> 5);
    const int row = n_g & 255;
    const int kkb0 = k0g & 31;
    const int Lc = row * 32 + kkb0;
    const int mask = ((row >> 2) & 3) << 3;
    const int addr0 = Lc ^ (mask & 16);
    uint8_t* p = wqt + slot * 8192;
    *(unsigned long long*)(p + addr0 + (mask & 8)) = L0;
    *(unsigned long long*)(p + addr0 + (8 ^ (mask & 8))) = L1;
  }
}

// ---------------------------------------------------------------------------
// fp8 GEMM, 256x256 tile, 16 waves (4x4), 32x32x64 MX MFMA, slice-ring:
//   4-slice ring per operand (16 KB slices), phase = one 64-k-byte slice,
//   lead-2 staging, counted vmcnt(2) (never 0), one barrier per phase.
// ---------------------------------------------------------------------------
#define T_BM 256
#define T_BN 256
#define UNIT_SCALE 0x7F7F7F7F

__device__ __forceinline__ void gl_lds16(const uint8_t* g, uint8_t* lds) {
  __builtin_amdgcn_global_load_lds(
      (const __attribute__((address_space(1))) void*)g,
      (__attribute__((address_space(3))) void*)lds, 16, 0, 0);
}

__global__ __launch_bounds__(1024, 4) void gemm_fp8_mx(
    const uint8_t* __restrict__ Aq, const uint8_t* __restrict__ BqT,
    const float* __restrict__ bias, const float* __restrict__ scales,
    float* __restrict__ C, int M, int N, int K) {
  extern __shared__ uint8_t smem[];
  uint8_t* const Ar = smem;            // 4 slices x 16384 = 64 KB
  uint8_t* const Br = smem + 65536;    // 4 slices x 16384 = 64 KB

  const int ntn = N / T_BN;
  const int bid = blockIdx.x;
  const int m0 = (bid / ntn) * T_BM;
  const int n0 = (bid % ntn) * T_BN;

  const int tid = threadIdx.x;
  const int w = tid >> 6;      // wave 0..15
  const int l = tid & 63;
  const int wr = w >> 2;       // 0..3  (M quarter)
  const int wc = w & 3;        // 0..3  (N quarter)

  const int kslots = K >> 5;

  // staging: linear contiguous copy of one 16 KB slice; wave w owns bytes
  // [w*1024, w*1024+1024), lane l the 16B at +l*16.
  const int soff = w * 1024 + l * 16;
  const uint8_t* a_src = Aq + (size_t)(m0 >> 8) * kslots * 8192 + soff;
  const uint8_t* b_src = BqT + (size_t)(n0 >> 8) * kslots * 8192 + soff;

  // fragment-read offsets: lane half h = l>>5 -> slot h within the slice.
  const int h = l >> 5;
  const int rl = l & 31;
  int aoff[2][4], boff[2][4];
#pragma unroll
  for (int mt = 0; mt < 2; ++mt) {
    const int ra = wr * 64 + mt * 32 + rl;
    const int rb = wc * 64 + mt * 32 + rl;
#pragma unroll
    for (int j = 0; j < 4; ++j) {
      aoff[mt][j] = h * 8192 + ra * 32 + ((j ^ ((ra >> 2) & 3)) * 8);
      boff[mt][j] = h * 8192 + rb * 32 + ((j ^ ((rb >> 2) & 3)) * 8);
    }
  }

  f32x16 acc[2][2];
#pragma unroll
  for (int i = 0; i < 2; ++i)
#pragma unroll
    for (int j = 0; j < 2; ++j) acc[i][j] = 0.f;

  const int NP = K >> 6;  // 64 phases (one 16 KB slice each)

  // prologue: stage slices 0,1 into ring slots 0,1
  gl_lds16(a_src, Ar + soff);
  gl_lds16(b_src, Br + soff);
  gl_lds16(a_src + 16384, Ar + 16384 + soff);
  gl_lds16(b_src + 16384, Br + 16384 + soff);
  asm volatile("s_waitcnt vmcnt(2)" ::: "memory");  // slice 0 landed
  __builtin_amdgcn_s_barrier();

  for (int p = 0; p < NP; ++p) {
    // 1. stage slice p+2 (tail: re-stage p-2 = same bytes into its dead slot)
    const int ss = (p + 2 < NP) ? (p + 2) : (p - 2);
    const int rslot = ((p + 2) & 3) * 16384;
    gl_lds16(a_src + (size_t)ss * 16384, Ar + rslot + soff);
    gl_lds16(b_src + (size_t)ss * 16384, Br + rslot + soff);

    // 2. fragments from ring slot p&3 (compiler-managed lgkmcnt)
    const uint8_t* Asl = Ar + (p & 3) * 16384;
    const uint8_t* Bsl = Br + (p & 3) * 16384;
    Frag32 af[2], bf[2];
#pragma unroll
    for (int t2 = 0; t2 < 2; ++t2)
#pragma unroll
      for (int j = 0; j < 4; ++j) {
        af[t2].l[j] = *(const long*)(Asl + aoff[t2][j]);
        bf[t2].l[j] = *(const long*)(Bsl + boff[t2][j]);
      }

    // 3. 4 MFMAs (64x64 per wave)
    __builtin_amdgcn_s_setprio(1);
    acc[0][0] = __builtin_amdgcn_mfma_scale_f32_32x32x64_f8f6f4(
        af[0].v, bf[0].v, acc[0][0], 0, 0, 0, UNIT_SCALE, 0, UNIT_SCALE);
    acc[1][0] = __builtin_amdgcn_mfma_scale_f32_32x32x64_f8f6f4(
        af[1].v, bf[0].v, acc[1][0], 0, 0, 0, UNIT_SCALE, 0, UNIT_SCALE);
    acc[0][1] = __builtin_amdgcn_mfma_scale_f32_32x32x64_f8f6f4(
        af[0].v, bf[1].v, acc[0][1], 0, 0, 0, UNIT_SCALE, 0, UNIT_SCALE);
    acc[1][1] = __builtin_amdgcn_mfma_scale_f32_32x32x64_f8f6f4(
        af[1].v, bf[1].v, acc[1][1], 0, 0, 0, UNIT_SCALE, 0, UNIT_SCALE);
    __builtin_amdgcn_s_setprio(0);

    // 4. counted wait: slice p+1 must land; slice p+2's pair stays in flight
    asm volatile("s_waitcnt vmcnt(2)" ::: "memory");
    __builtin_amdgcn_s_barrier();
  }
  asm volatile("s_waitcnt vmcnt(0)" ::: "memory");  // drain tail dummies

  // epilogue: C = acc * (x_scale*w_scale) + bias
  // 32x32 C/D layout: col = l&31, row = (r&3) + 8*(r>>2) + 4*(l>>5)
  const float s = scales[4];
  const int colb = n0 + wc * 64 + rl;
  const int rowb = m0 + wr * 64 + 4 * h;
#pragma unroll
  for (int nt = 0; nt < 2; ++nt) {
    const int col = colb + nt * 32;
    const float bv = bias[col];
#pragma unroll
    for (int mt = 0; mt < 2; ++mt) {
#pragma unroll
      for (int r = 0; r < 16; ++r) {
        const int row = rowb + mt * 32 + (r & 3) + 8 * (r >> 2);
        C[(size_t)row * N + col] = acc[mt][nt][r] * s + bv;
      }
    }
  }
}

extern "C" void kernel_launch(void* const* d_in, const int* in_sizes, int n_in,
                              void* d_out, int out_size, void* d_ws, size_t ws_size,
                              hipStream_t stream) {
  const float* inp = (const float*)d_in[0];
  const float* weight = (const float*)d_in[1];
  const float* bias = (const float*)d_in[2];
  float* out = (float*)d_out;

  const int N = in_sizes[2];                 // 16384
  const int K = in_sizes[1] / N;             // 4096
  const int M = in_sizes[0] / K;             // 8192

  uint8_t* ws = (uint8_t*)d_ws;
  float* scales = (float*)ws;
  uint8_t* xq = ws + 256;
  uint8_t* wqt = ws + 256 + (size_t)M * K;

  hipMemsetAsync(d_ws, 0, 256, stream);

  absmax_kernel<<<2048, 256, 0, stream>>>((const float4*)weight,
                                          (size_t)K * N / 4,
                                          (unsigned int*)ws + 0);
  absmax_kernel<<<2048, 256, 0, stream>>>((const float4*)inp,
                                          (size_t)M * K / 4,
                                          (unsigned int*)ws + 1);
  scales_kernel<<<1, 1, 0, stream>>>(scales);

  quantize_x_kernel<<<4096, 256, 0, stream>>>((const float4*)inp, xq, scales,
                                              K, M * K / 16);
  quantize_wT_kernel<<<dim3(N / 64, K / 64), 256, 0, stream>>>(weight, wqt,
                                                               scales, N, K);

  gemm_fp8_mx<<<(M / T_BM) * (N / T_BN), 1024, 131072, stream>>>(
      xq, wqt, bias, scales, out, M, N, K);
}